// Round 2
// baseline (765.492 us; speedup 1.0000x reference)
//
#include <hip/hip_runtime.h>
#include <hip/hip_bf16.h>
#include <hip/hip_cooperative_groups.h>
#include <math.h>
#include <type_traits>

namespace cg = cooperative_groups;

// MoE: E=16, D=H=768, T=6304 tokens; fp32 in/out, bf16 internally for MFMA.
#define T_TOK 6304
#define DMODEL 768
#define NEXP 16
#define NGATE 394            // 6304 / 16 tokens per gate unit
#define N8G 1179648          // 768*768*16 / 8 floats-per-thread units per weight matrix
#define COOP_GRID 768        // 3 blocks/CU × 256 CU: co-resident by construction
                             // (LDS 39.3KB×3=118KB ≤160KB; launch_bounds caps VGPR≤128)

typedef __bf16 bf16x8 __attribute__((ext_vector_type(8)));
typedef float f32x4 __attribute__((ext_vector_type(4)));

__device__ __forceinline__ unsigned short f2bf(float f) {
    __hip_bfloat16 b = __float2bfloat16(f);   // RNE
    return __builtin_bit_cast(unsigned short, b);
}
__device__ __forceinline__ unsigned int pack2(float lo, float hi) {
    return (unsigned int)f2bf(lo) | ((unsigned int)f2bf(hi) << 16);
}

// ---------------- shared memory layout (one struct reused by all phases) ----------
struct SMem {
    unsigned short At[2][64][72];   // 18,432 B  (pad 72: 2-way bank alias, free)
    unsigned short Bt[2][64][72];   // 18,432 B
    int toks[64];                   //    256 B
    double lg[16][17];              //  2,176 B   -> 39,296 B total
};

// ---------------- gate: 16 tokens x 16 experts per unit; fp64 dot, np argmax ------
__device__ void gate_unit(int gb, const float* __restrict__ x,
                          const float* __restrict__ Wg, const float* __restrict__ bg,
                          int* cnt, int* list, unsigned short* xb, SMem& sm)
{
    const int tt = threadIdx.x >> 4;
    const int e  = threadIdx.x & 15;
    const int t  = gb * 16 + tt;
    const float4* xr = (const float4*)(x + (size_t)t * DMODEL);
    const float4* wr = (const float4*)(Wg + (size_t)e * DMODEL);
    double s0 = 0, s1 = 0, s2 = 0, s3 = 0;
#pragma unroll 4
    for (int i = 0; i < DMODEL / 4; ++i) {
        float4 a = xr[i], w = wr[i];
        s0 += (double)a.x * (double)w.x;
        s1 += (double)a.y * (double)w.y;
        s2 += (double)a.z * (double)w.z;
        s3 += (double)a.w * (double)w.w;
    }
    sm.lg[tt][e] = (s0 + s1) + (s2 + s3);
    // emit x row slice [e*48, e*48+48) as bf16
    uint4* dst = (uint4*)(xb + (size_t)t * DMODEL + e * 48);
#pragma unroll
    for (int u = 0; u < 6; ++u) {
        float4 a = xr[e * 12 + 2 * u], b = xr[e * 12 + 2 * u + 1];
        dst[u] = make_uint4(pack2(a.x, a.y), pack2(a.z, a.w),
                            pack2(b.x, b.y), pack2(b.z, b.w));
    }
    __syncthreads();
    if (e == 0) {
        double best = -1e300; int bi = 0;
#pragma unroll
        for (int k = 0; k < NEXP; ++k) {
            double v = sm.lg[tt][k] + (double)bg[k];
            if (v > best) { best = v; bi = k; }
        }
        int pos = atomicAdd(&cnt[bi], 1);      // device-scope: cross-XCD safe
        list[bi * T_TOK + pos] = t;
    }
    __syncthreads();                            // lg reuse safety across gb iters
}

// ---------------- gathered expert GEMM phase ---------------------------------------
// BM=BN=BK=64, 4 waves, wave tile 32x32, double-buffered LDS, 1 barrier per K-iter.
// SWAPPED MFMA operands: acc[i][j] = mfma(w_frag_j, tok_frag_i, acc):
//   D row = (lane>>4)*4+reg = weight col (contiguous 4), D col = lane&15 = token.
// Each lane stores 4 consecutive out cols of one token row: 8B (bf16) / 16B (fp32).
// PACKED_IN : A rows are off[e]+row (dense, sequential) instead of gathered tokens.
// PACKED_OUT: out rows are off[e]+row (dense) instead of scattered by token id.
template<int GELU, int PACKED_IN, int PACKED_OUT, typename TOUT>
__device__ void layer_pass(const unsigned short* __restrict__ in,
                           const unsigned short* __restrict__ Wb,
                           const float* __restrict__ bias,
                           const int* __restrict__ cnt, const int* __restrict__ list,
                           TOUT* __restrict__ outp, SMem& sm)
{
    const int tid = threadIdx.x, lane = tid & 63, w = tid >> 6;
    const int rg = w & 1, cgp = w >> 1;
    const int l15 = lane & 15, q8 = (lane >> 4) * 8, q = lane >> 4;
    const int sr = tid >> 2, sk = (tid & 3) * 16;

    for (int item = blockIdx.x; item < NEXP * 12 * 8; item += gridDim.x) {
        // consecutive blocks -> distinct (e,nb) weight panels (XCD spread), like old grid
        const int ys = item / 192, rem = item % 192, e = rem / 12, nb = rem % 12;
        const int c = cnt[e];
        int off = 0;
        if (PACKED_IN || PACKED_OUT)
            for (int k = 0; k < e; ++k) off += cnt[k];   // prefix base of expert e
        const int n0 = nb * 64;
        const unsigned short* bsrc =
            Wb + (size_t)e * DMODEL * DMODEL + (size_t)(n0 + sr) * DMODEL + sk;
        const int* lst = list + e * T_TOK;

        for (int yt = ys; yt * 64 < c; yt += 8) {
            const int m0 = yt * 64;
            __syncthreads();                 // prior tile epilogue done (toks/LDS reuse)
            if (!PACKED_OUT && tid < 64) {
                int mi = m0 + tid;
                sm.toks[tid] = lst[mi < c ? mi : c - 1];
            }
            const int ma0 = m0 + sr;
            const int mac = ma0 < c ? ma0 : c - 1;
            const unsigned short* asrc = PACKED_IN
                ? in + (size_t)(off + mac) * DMODEL + sk
                : in + (size_t)lst[mac] * DMODEL + sk;

            f32x4 acc[2][2];
#pragma unroll
            for (int i = 0; i < 2; ++i)
#pragma unroll
                for (int j = 0; j < 2; ++j) acc[i][j] = (f32x4){0.f, 0.f, 0.f, 0.f};

            uint4 pa[2], pb[2];
            auto load_regs = [&](int k0) {
                const uint4* s = (const uint4*)(asrc + k0);
                pa[0] = s[0]; pa[1] = s[1];
                const uint4* t2 = (const uint4*)(bsrc + k0);
                pb[0] = t2[0]; pb[1] = t2[1];
            };
            auto store_tiles = [&](int buf) {
                *(uint4*)&sm.At[buf][sr][sk] = pa[0];
                *(uint4*)&sm.At[buf][sr][sk + 8] = pa[1];
                *(uint4*)&sm.Bt[buf][sr][sk] = pb[0];
                *(uint4*)&sm.Bt[buf][sr][sk + 8] = pb[1];
            };

            load_regs(0);
            store_tiles(0);
#pragma unroll 1
            for (int it = 0; it < DMODEL / 64; ++it) {
                __syncthreads();             // buf[it&1] ready
                if (it + 1 < DMODEL / 64) load_regs((it + 1) * 64);
                const int buf = it & 1;
#pragma unroll
                for (int kk = 0; kk < 64; kk += 32) {
                    bf16x8 a0 = *(const bf16x8*)&sm.At[buf][rg * 32 + l15][kk + q8];
                    bf16x8 a1 = *(const bf16x8*)&sm.At[buf][rg * 32 + 16 + l15][kk + q8];
                    bf16x8 b0 = *(const bf16x8*)&sm.Bt[buf][cgp * 32 + l15][kk + q8];
                    bf16x8 b1 = *(const bf16x8*)&sm.Bt[buf][cgp * 32 + 16 + l15][kk + q8];
                    acc[0][0] = __builtin_amdgcn_mfma_f32_16x16x32_bf16(b0, a0, acc[0][0], 0, 0, 0);
                    acc[0][1] = __builtin_amdgcn_mfma_f32_16x16x32_bf16(b1, a0, acc[0][1], 0, 0, 0);
                    acc[1][0] = __builtin_amdgcn_mfma_f32_16x16x32_bf16(b0, a1, acc[1][0], 0, 0, 0);
                    acc[1][1] = __builtin_amdgcn_mfma_f32_16x16x32_bf16(b1, a1, acc[1][1], 0, 0, 0);
                }
                if (it + 1 < DMODEL / 64) store_tiles(buf ^ 1);  // peers read buf only
            }

            // epilogue: lane's token row = rg*32+i*16+l15; cols colb..colb+3 contiguous
#pragma unroll
            for (int i = 0; i < 2; ++i) {
                const int mrow = rg * 32 + i * 16 + l15;
                if (m0 + mrow < c) {
                    const size_t rb = PACKED_OUT
                        ? (size_t)(off + m0 + mrow) * DMODEL
                        : (size_t)sm.toks[mrow] * DMODEL;
#pragma unroll
                    for (int j = 0; j < 2; ++j) {
                        const int colb = n0 + cgp * 32 + j * 16 + q * 4;
                        const float4 bv = *(const float4*)&bias[e * DMODEL + colb];
                        float v0 = acc[i][j][0] + bv.x;
                        float v1 = acc[i][j][1] + bv.y;
                        float v2 = acc[i][j][2] + bv.z;
                        float v3 = acc[i][j][3] + bv.w;
                        if (GELU) {
                            v0 = 0.5f * v0 * (1.f + erff(v0 * 0.70710678118654752f));
                            v1 = 0.5f * v1 * (1.f + erff(v1 * 0.70710678118654752f));
                            v2 = 0.5f * v2 * (1.f + erff(v2 * 0.70710678118654752f));
                            v3 = 0.5f * v3 * (1.f + erff(v3 * 0.70710678118654752f));
                        }
                        if constexpr (std::is_same<TOUT, float>::value) {
                            *(float4*)&outp[rb + colb] = make_float4(v0, v1, v2, v3);
                        } else {
                            uint2 p; p.x = pack2(v0, v1); p.y = pack2(v2, v3);
                            *(uint2*)&outp[rb + colb] = p;
                        }
                    }
                }
            }
        }
    }
}

// ---------------- fused single-dispatch cooperative kernel -------------------------
__global__ __launch_bounds__(256, 4) void fused_moe(
    const float* __restrict__ x, const float* __restrict__ W1,
    const float* __restrict__ b1, const float* __restrict__ W2,
    const float* __restrict__ b2, const float* __restrict__ Wg,
    const float* __restrict__ bg, int* cnt, int* list,
    unsigned short* xb, unsigned short* h,
    unsigned short* w1b, unsigned short* w2b, float* out)
{
    __shared__ SMem sm;
    // Phase A1: gate (+x->bf16), strided over blocks
    for (int gb = blockIdx.x; gb < NGATE; gb += gridDim.x)
        gate_unit(gb, x, Wg, bg, cnt, list, xb, sm);
    // Phase A2: W1|W2 -> bf16, all blocks strided (8 floats/thread/iter)
    for (size_t i = (size_t)blockIdx.x * 256 + threadIdx.x; i < 2 * (size_t)N8G;
         i += (size_t)gridDim.x * 256) {
        const float4* s; uint4* d; size_t j;
        if (i < (size_t)N8G) { s = (const float4*)W1; d = (uint4*)w1b; j = i; }
        else                 { s = (const float4*)W2; d = (uint4*)w2b; j = i - N8G; }
        float4 a = s[2 * j], b = s[2 * j + 1];
        d[j] = make_uint4(pack2(a.x, a.y), pack2(a.z, a.w),
                          pack2(b.x, b.y), pack2(b.z, b.w));
    }
    __threadfence();
    cg::this_grid().sync();     // lists + bf16 weights/x visible grid-wide
    layer_pass<1, 0, 1, unsigned short>(xb, w1b, b1, cnt, list, h, sm);
    __threadfence();
    cg::this_grid().sync();     // packed h visible grid-wide
    layer_pass<0, 1, 0, float>(h, w2b, b2, cnt, list, out, sm);
}

// ---------------- standalone wrappers (fallback 3-kernel path) ---------------------
template<int GELU, int PACKED_IN, int PACKED_OUT, typename TOUT>
__global__ __launch_bounds__(256, 4) void expert_wrap(
    const unsigned short* __restrict__ in, const unsigned short* __restrict__ Wb,
    const float* __restrict__ bias, const int* __restrict__ cnt,
    const int* __restrict__ list, TOUT* __restrict__ outp)
{
    __shared__ SMem sm;
    layer_pass<GELU, PACKED_IN, PACKED_OUT, TOUT>(in, Wb, bias, cnt, list, outp, sm);
}

__global__ __launch_bounds__(256) void prep_kernel(
    const float* __restrict__ x, const float* __restrict__ Wg,
    const float* __restrict__ bg, const float* __restrict__ W1,
    const float* __restrict__ W2, int* __restrict__ cnt, int* __restrict__ list,
    unsigned short* __restrict__ xb, unsigned short* __restrict__ w1b,
    unsigned short* __restrict__ w2b)
{
    if (blockIdx.x >= NGATE) {
        int i = (blockIdx.x - NGATE) * 256 + threadIdx.x;
        const float4* s; uint4* d; int j;
        if (i < N8G) { s = (const float4*)W1; d = (uint4*)w1b; j = i; }
        else         { s = (const float4*)W2; d = (uint4*)w2b; j = i - N8G; }
        float4 a = s[2 * j], b = s[2 * j + 1];
        d[j] = make_uint4(pack2(a.x, a.y), pack2(a.z, a.w),
                          pack2(b.x, b.y), pack2(b.z, b.w));
        return;
    }
    __shared__ double lg[16][17];
    const int tt = threadIdx.x >> 4;
    const int e  = threadIdx.x & 15;
    const int t  = blockIdx.x * 16 + tt;
    const float4* xr = (const float4*)(x + (size_t)t * DMODEL);
    const float4* wr = (const float4*)(Wg + (size_t)e * DMODEL);
    double s0 = 0, s1 = 0, s2 = 0, s3 = 0;
#pragma unroll 4
    for (int i = 0; i < DMODEL / 4; ++i) {
        float4 a = xr[i], w = wr[i];
        s0 += (double)a.x * (double)w.x;
        s1 += (double)a.y * (double)w.y;
        s2 += (double)a.z * (double)w.z;
        s3 += (double)a.w * (double)w.w;
    }
    lg[tt][e] = (s0 + s1) + (s2 + s3);
    if (xb) {
        uint4* dst = (uint4*)(xb + (size_t)t * DMODEL + e * 48);
#pragma unroll
        for (int u = 0; u < 6; ++u) {
            float4 a = xr[e * 12 + 2 * u], b = xr[e * 12 + 2 * u + 1];
            dst[u] = make_uint4(pack2(a.x, a.y), pack2(a.z, a.w),
                                pack2(b.x, b.y), pack2(b.z, b.w));
        }
    }
    __syncthreads();
    if (e == 0) {
        double best = -1e300; int bi = 0;
#pragma unroll
        for (int k = 0; k < NEXP; ++k) {
            double v = lg[tt][k] + (double)bg[k];
            if (v > best) { best = v; bi = k; }
        }
        int pos = atomicAdd(&cnt[bi], 1);
        list[bi * T_TOK + pos] = t;
    }
}

// ---------------- legacy small-workspace kernels (proven, verbatim semantics) ------
template<int GELU, typename TA, typename TW, typename TOUT>
__global__ __launch_bounds__(256, 4) void expert_layer(
    const TA* __restrict__ in, const TW* __restrict__ W,
    const float* __restrict__ bias, const int* __restrict__ cnt,
    const int* __restrict__ list, TOUT* __restrict__ outp)
{
    constexpr int BK = 64, LDK = 72;
    constexpr bool A_F32 = std::is_same<TA, float>::value;
    constexpr bool W_F32 = std::is_same<TW, float>::value;
    __shared__ __align__(16) unsigned short At[2][64][LDK];
    __shared__ __align__(16) unsigned short Bt[2][64][LDK];
    __shared__ int toks[64];

    const int bx = blockIdx.x;
    const int e = bx / 12, nb = bx % 12;
    const int c = cnt[e];
    const int n0 = nb * 64;
    const int tid = threadIdx.x, lane = tid & 63, w = tid >> 6;
    const int rg = w & 1, cgp = w >> 1;
    const int l15 = lane & 15, q8 = (lane >> 4) * 8, q = lane >> 4;
    const int sr = tid >> 2, sk = (tid & 3) * 16;

    const TW* bsrc = W + (size_t)e * DMODEL * DMODEL + (size_t)(n0 + sr) * DMODEL + sk;
    const int* lst = list + e * T_TOK;

    uint4 pa[2], pb[2];
    float4 fa[4], fb[4];

    for (int yt = blockIdx.y; yt * 64 < c; yt += 8) {
        const int m0 = yt * 64;
        __syncthreads();
        if (tid < 64) {
            int mi = m0 + tid;
            toks[tid] = lst[mi < c ? mi : c - 1];
        }
        int ma = m0 + sr;
        const TA* asrc = in + (size_t)lst[ma < c ? ma : c - 1] * DMODEL + sk;

        f32x4 acc[2][2];
#pragma unroll
        for (int i = 0; i < 2; ++i)
#pragma unroll
            for (int j = 0; j < 2; ++j) acc[i][j] = (f32x4){0.f, 0.f, 0.f, 0.f};

        auto load_regs = [&](int k0) {
            if constexpr (A_F32) {
                const float4* s = (const float4*)(asrc + k0);
                fa[0] = s[0]; fa[1] = s[1]; fa[2] = s[2]; fa[3] = s[3];
            } else {
                const uint4* s = (const uint4*)(asrc + k0);
                pa[0] = s[0]; pa[1] = s[1];
            }
            if constexpr (W_F32) {
                const float4* s = (const float4*)(bsrc + k0);
                fb[0] = s[0]; fb[1] = s[1]; fb[2] = s[2]; fb[3] = s[3];
            } else {
                const uint4* s = (const uint4*)(bsrc + k0);
                pb[0] = s[0]; pb[1] = s[1];
            }
        };
        auto store_tiles = [&](int buf) {
            if constexpr (A_F32) {
                uint4 w0, w1;
                w0.x = pack2(fa[0].x, fa[0].y); w0.y = pack2(fa[0].z, fa[0].w);
                w0.z = pack2(fa[1].x, fa[1].y); w0.w = pack2(fa[1].z, fa[1].w);
                w1.x = pack2(fa[2].x, fa[2].y); w1.y = pack2(fa[2].z, fa[2].w);
                w1.z = pack2(fa[3].x, fa[3].y); w1.w = pack2(fa[3].z, fa[3].w);
                *(uint4*)&At[buf][sr][sk] = w0; *(uint4*)&At[buf][sr][sk + 8] = w1;
            } else {
                *(uint4*)&At[buf][sr][sk] = pa[0]; *(uint4*)&At[buf][sr][sk + 8] = pa[1];
            }
            if constexpr (W_F32) {
                uint4 w0, w1;
                w0.x = pack2(fb[0].x, fb[0].y); w0.y = pack2(fb[0].z, fb[0].w);
                w0.z = pack2(fb[1].x, fb[1].y); w0.w = pack2(fb[1].z, fb[1].w);
                w1.x = pack2(fb[2].x, fb[2].y); w1.y = pack2(fb[2].z, fb[2].w);
                w1.z = pack2(fb[3].x, fb[3].y); w1.w = pack2(fb[3].z, fb[3].w);
                *(uint4*)&Bt[buf][sr][sk] = w0; *(uint4*)&Bt[buf][sr][sk + 8] = w1;
            } else {
                *(uint4*)&Bt[buf][sr][sk] = pb[0]; *(uint4*)&Bt[buf][sr][sk + 8] = pb[1];
            }
        };

        load_regs(0);
        store_tiles(0);
#pragma unroll 1
        for (int it = 0; it < DMODEL / BK; ++it) {
            __syncthreads();
            if (it + 1 < DMODEL / BK) load_regs((it + 1) * BK);
            const int buf = it & 1;
#pragma unroll
            for (int kk = 0; kk < BK; kk += 32) {
                bf16x8 a0 = *(const bf16x8*)&At[buf][rg * 32 + l15][kk + q8];
                bf16x8 a1 = *(const bf16x8*)&At[buf][rg * 32 + 16 + l15][kk + q8];
                bf16x8 b0 = *(const bf16x8*)&Bt[buf][cgp * 32 + l15][kk + q8];
                bf16x8 b1 = *(const bf16x8*)&Bt[buf][cgp * 32 + 16 + l15][kk + q8];
                acc[0][0] = __builtin_amdgcn_mfma_f32_16x16x32_bf16(a0, b0, acc[0][0], 0, 0, 0);
                acc[0][1] = __builtin_amdgcn_mfma_f32_16x16x32_bf16(a0, b1, acc[0][1], 0, 0, 0);
                acc[1][0] = __builtin_amdgcn_mfma_f32_16x16x32_bf16(a1, b0, acc[1][0], 0, 0, 0);
                acc[1][1] = __builtin_amdgcn_mfma_f32_16x16x32_bf16(a1, b1, acc[1][1], 0, 0, 0);
            }
            if (it + 1 < DMODEL / BK) store_tiles(buf ^ 1);
        }

#pragma unroll
        for (int i = 0; i < 2; ++i) {
#pragma unroll
            for (int j = 0; j < 2; ++j) {
                int col = n0 + cgp * 32 + j * 16 + l15;
                float bv = bias[e * DMODEL + col];
#pragma unroll
                for (int r = 0; r < 4; ++r) {
                    int mrow = rg * 32 + i * 16 + q * 4 + r;
                    if (m0 + mrow < c) {
                        float val = acc[i][j][r] + bv;
                        if (GELU) val = 0.5f * val * (1.f + erff(val * 0.70710678118654752f));
                        size_t idx = (size_t)toks[mrow] * DMODEL + col;
                        if constexpr (std::is_same<TOUT, float>::value) outp[idx] = val;
                        else outp[idx] = f2bf(val);
                    }
                }
            }
        }
    }
}

// ---------------- launch -----------------------------------------------------------
extern "C" void kernel_launch(void* const* d_in, const int* in_sizes, int n_in,
                              void* d_out, int out_size, void* d_ws, size_t ws_size,
                              hipStream_t stream)
{
    const float* x  = (const float*)d_in[0];
    const float* W1 = (const float*)d_in[1];
    const float* b1 = (const float*)d_in[2];
    const float* W2 = (const float*)d_in[3];
    const float* b2 = (const float*)d_in[4];
    const float* Wg = (const float*)d_in[5];
    const float* bg = (const float*)d_in[6];
    float* out = (float*)d_out;

    char* ws   = (char*)d_ws;
    int*  cnt  = (int*)ws;                                  // 64 B
    int*  list = (int*)(ws + 256);                          // 403,456 B
    unsigned short* xb  = (unsigned short*)(ws + 403712);   // 9,682,944 B
    unsigned short* h   = (unsigned short*)(ws + 10086656); // 9,682,944 B
    unsigned short* w1b = (unsigned short*)(ws + 19769600); // 18,874,368 B
    unsigned short* w2b = (unsigned short*)(ws + 38643968); // 18,874,368 B
    const bool big = ws_size >= (size_t)57518336;

    hipMemsetAsync(cnt, 0, 256, stream);

    if (big) {
        // single-dispatch cooperative path: fixed 768-block grid, no host queries
        void* args[] = {(void*)&x,  (void*)&W1, (void*)&b1, (void*)&W2, (void*)&b2,
                        (void*)&Wg, (void*)&bg, (void*)&cnt, (void*)&list,
                        (void*)&xb, (void*)&h,  (void*)&w1b, (void*)&w2b, (void*)&out};
        hipError_t err = hipLaunchCooperativeKernel((const void*)fused_moe,
                                                    dim3(COOP_GRID), dim3(256),
                                                    args, 0, stream);
        if (err == hipSuccess) return;
        // cooperative launch rejected -> improved 3-kernel path (same device code)
        prep_kernel<<<dim3(NGATE + 9216), dim3(256), 0, stream>>>(
            x, Wg, bg, W1, W2, cnt, list, xb, w1b, w2b);
        expert_wrap<1, 0, 1, unsigned short>
            <<<dim3(1536), dim3(256), 0, stream>>>(xb, w1b, b1, cnt, list, h);
        expert_wrap<0, 1, 0, float>
            <<<dim3(1536), dim3(256), 0, stream>>>(h, w2b, b2, cnt, list, out);
        return;
    }

    // small-workspace fallback: fp32 inputs with fused bf16 staging (proven path)
    prep_kernel<<<dim3(NGATE), dim3(256), 0, stream>>>(
        x, Wg, bg, W1, W2, cnt, list, nullptr, nullptr, nullptr);
    dim3 grid(12 * NEXP, 8);
    expert_layer<1, float, float, unsigned short>
        <<<grid, dim3(256), 0, stream>>>(x, W1, b1, cnt, list, h);
    expert_layer<0, unsigned short, float, float>
        <<<grid, dim3(256), 0, stream>>>(h, W2, b2, cnt, list, out);
}

// Round 3
// 347.313 us; speedup vs baseline: 2.2040x; 2.2040x over previous
//
#include <hip/hip_runtime.h>
#include <hip/hip_bf16.h>
#include <math.h>
#include <type_traits>

// MoE: E=16, D=H=768, T=6304 tokens; fp32 in/out, bf16 internally for MFMA.
#define T_TOK 6304
#define DMODEL 768
#define NEXP 16
#define NGATE 394            // 6304 / 16 tokens per gate unit
#define N8G 1179648          // 768*768*16 / 8 8-float units per weight matrix

typedef __bf16 bf16x8 __attribute__((ext_vector_type(8)));
typedef float f32x4 __attribute__((ext_vector_type(4)));

__device__ __forceinline__ unsigned short f2bf(float f) {
    __hip_bfloat16 b = __float2bfloat16(f);   // RNE
    return __builtin_bit_cast(unsigned short, b);
}
__device__ __forceinline__ unsigned int pack2(float lo, float hi) {
    return (unsigned int)f2bf(lo) | ((unsigned int)f2bf(hi) << 16);
}

// ---------- prep: blocks [0,394) = gate (+x->bf16); [394,9610) = W1|W2 -> bf16 -------
__global__ __launch_bounds__(256) void prep_kernel(
    const float* __restrict__ x, const float* __restrict__ Wg,
    const float* __restrict__ bg, const float* __restrict__ W1,
    const float* __restrict__ W2, int* __restrict__ cnt, int* __restrict__ list,
    unsigned short* __restrict__ xb, unsigned short* __restrict__ w1b,
    unsigned short* __restrict__ w2b)
{
    if (blockIdx.x >= NGATE) {               // weight convert: 8 floats/thread
        int i = (blockIdx.x - NGATE) * 256 + threadIdx.x;   // [0, 2*N8G)
        const float4* s; uint4* d; int j;
        if (i < N8G) { s = (const float4*)W1; d = (uint4*)w1b; j = i; }
        else         { s = (const float4*)W2; d = (uint4*)w2b; j = i - N8G; }
        float4 a = s[2 * j], b = s[2 * j + 1];
        d[j] = make_uint4(pack2(a.x, a.y), pack2(a.z, a.w),
                          pack2(b.x, b.y), pack2(b.z, b.w));
        return;
    }
    // gate: thread=(token,expert), fp64 dot, strict first-max argmax (np semantics)
    __shared__ double lg[16][17];
    const int tt = threadIdx.x >> 4;
    const int e  = threadIdx.x & 15;
    const int t  = blockIdx.x * 16 + tt;     // 6304 = 394*16
    const float4* xr = (const float4*)(x + (size_t)t * DMODEL);
    const float4* wr = (const float4*)(Wg + (size_t)e * DMODEL);
    double s0 = 0, s1 = 0, s2 = 0, s3 = 0;
#pragma unroll 4
    for (int i = 0; i < DMODEL / 4; ++i) {
        float4 a = xr[i], w = wr[i];
        s0 += (double)a.x * (double)w.x;
        s1 += (double)a.y * (double)w.y;
        s2 += (double)a.z * (double)w.z;
        s3 += (double)a.w * (double)w.w;
    }
    lg[tt][e] = (s0 + s1) + (s2 + s3);
    if (xb) {   // emit x row slice [e*48, e*48+48) as bf16
        uint4* dst = (uint4*)(xb + (size_t)t * DMODEL + e * 48);
#pragma unroll
        for (int u = 0; u < 6; ++u) {
            float4 a = xr[e * 12 + 2 * u], b = xr[e * 12 + 2 * u + 1];
            dst[u] = make_uint4(pack2(a.x, a.y), pack2(a.z, a.w),
                                pack2(b.x, b.y), pack2(b.z, b.w));
        }
    }
    __syncthreads();
    if (e == 0) {
        double best = -1e300; int bi = 0;
#pragma unroll
        for (int k = 0; k < NEXP; ++k) {
            double v = lg[tt][k] + (double)bg[k];
            if (v > best) { best = v; bi = k; }
        }
        int pos = atomicAdd(&cnt[bi], 1);
        list[bi * T_TOK + pos] = t;
    }
}

// ---------- gathered expert GEMM: proven (192,8) persistent-y structure -------------
// BM=BN=BK=64, 4 waves, wave tile 32x32, double-buffered LDS, 1 barrier per K-iter.
// SWAPPED MFMA operands: acc[i][j] = mfma(w_frag_j, tok_frag_i, acc) =>
//   D col = lane&15 = token-row-in-16, D row = (lane>>4)*4+reg = weight col (4 contig).
// Each lane stores 4 consecutive out cols of one token row: 8B (bf16) / 16B (fp32),
// replacing the old 2B/4B scalar scatter (the 15x HBM write amplification).
// PACKED_IN : A rows dense at off[e]+row (list order). PACKED_OUT: same for output.
template<int GELU, int PACKED_IN, int PACKED_OUT, typename TOUT>
__global__ __launch_bounds__(256, 4) void expert_gemm(
    const unsigned short* __restrict__ in, const unsigned short* __restrict__ Wb,
    const float* __restrict__ bias, const int* __restrict__ cnt,
    const int* __restrict__ list, TOUT* __restrict__ outp)
{
    constexpr int BK = 64, LDK = 72;   // pad 72: 144B row stride, 2-way alias (free)
    __shared__ __align__(16) unsigned short At[2][64][LDK];
    __shared__ __align__(16) unsigned short Bt[2][64][LDK];
    __shared__ int toks[64];

    const int bx = blockIdx.x;              // = e*12 + nb : consecutive bx spread XCDs
    const int e = bx / 12, nb = bx % 12;
    const int c = cnt[e];
    int off = 0;
    if (PACKED_IN || PACKED_OUT)
        for (int k = 0; k < e; ++k) off += cnt[k];   // prefix base of expert e
    const int n0 = nb * 64;
    const int tid = threadIdx.x, lane = tid & 63, w = tid >> 6;
    const int rg = w & 1, cgp = w >> 1;
    const int l15 = lane & 15, q8 = (lane >> 4) * 8, q = lane >> 4;
    const int sr = tid >> 2, sk = (tid & 3) * 16;

    const unsigned short* bsrc =
        Wb + (size_t)e * DMODEL * DMODEL + (size_t)(n0 + sr) * DMODEL + sk;
    const int* lst = list + e * T_TOK;

    uint4 pa[2], pb[2];

    for (int yt = blockIdx.y; yt * 64 < c; yt += 8) {
        const int m0 = yt * 64;
        __syncthreads();                     // prior y-iter epilogue done (LDS reuse)
        if (!PACKED_OUT && tid < 64) {
            int mi = m0 + tid;
            toks[tid] = lst[mi < c ? mi : c - 1];
        }
        const int ma0 = m0 + sr;
        const int mac = ma0 < c ? ma0 : c - 1;
        const unsigned short* asrc = PACKED_IN
            ? in + (size_t)(off + mac) * DMODEL + sk
            : in + (size_t)lst[mac] * DMODEL + sk;

        f32x4 acc[2][2];
#pragma unroll
        for (int i = 0; i < 2; ++i)
#pragma unroll
            for (int j = 0; j < 2; ++j) acc[i][j] = (f32x4){0.f, 0.f, 0.f, 0.f};

        auto load_regs = [&](int k0) {
            const uint4* s = (const uint4*)(asrc + k0);
            pa[0] = s[0]; pa[1] = s[1];
            const uint4* t2 = (const uint4*)(bsrc + k0);
            pb[0] = t2[0]; pb[1] = t2[1];
        };
        auto store_tiles = [&](int buf) {
            *(uint4*)&At[buf][sr][sk] = pa[0]; *(uint4*)&At[buf][sr][sk + 8] = pa[1];
            *(uint4*)&Bt[buf][sr][sk] = pb[0]; *(uint4*)&Bt[buf][sr][sk + 8] = pb[1];
        };

        load_regs(0);
        store_tiles(0);
#pragma unroll 1
        for (int it = 0; it < DMODEL / BK; ++it) {
            __syncthreads();                 // buf[it&1] ready
            if (it + 1 < DMODEL / BK) load_regs((it + 1) * BK);
            const int buf = it & 1;
#pragma unroll
            for (int kk = 0; kk < BK; kk += 32) {
                bf16x8 a0 = *(const bf16x8*)&At[buf][rg * 32 + l15][kk + q8];
                bf16x8 a1 = *(const bf16x8*)&At[buf][rg * 32 + 16 + l15][kk + q8];
                bf16x8 b0 = *(const bf16x8*)&Bt[buf][cgp * 32 + l15][kk + q8];
                bf16x8 b1 = *(const bf16x8*)&Bt[buf][cgp * 32 + 16 + l15][kk + q8];
                acc[0][0] = __builtin_amdgcn_mfma_f32_16x16x32_bf16(b0, a0, acc[0][0], 0, 0, 0);
                acc[0][1] = __builtin_amdgcn_mfma_f32_16x16x32_bf16(b1, a0, acc[0][1], 0, 0, 0);
                acc[1][0] = __builtin_amdgcn_mfma_f32_16x16x32_bf16(b0, a1, acc[1][0], 0, 0, 0);
                acc[1][1] = __builtin_amdgcn_mfma_f32_16x16x32_bf16(b1, a1, acc[1][1], 0, 0, 0);
            }
            if (it + 1 < DMODEL / BK) store_tiles(buf ^ 1);  // peers read buf only
        }

        // epilogue: lane's token row = rg*32+i*16+l15; cols colb..colb+3 contiguous
#pragma unroll
        for (int i = 0; i < 2; ++i) {
            const int mrow = rg * 32 + i * 16 + l15;
            if (m0 + mrow < c) {
                const size_t rb = PACKED_OUT
                    ? (size_t)(off + m0 + mrow) * DMODEL
                    : (size_t)toks[mrow] * DMODEL;
#pragma unroll
                for (int j = 0; j < 2; ++j) {
                    const int colb = n0 + cgp * 32 + j * 16 + q * 4;
                    const float4 bv = *(const float4*)&bias[e * DMODEL + colb];
                    float v0 = acc[i][j][0] + bv.x;
                    float v1 = acc[i][j][1] + bv.y;
                    float v2 = acc[i][j][2] + bv.z;
                    float v3 = acc[i][j][3] + bv.w;
                    if (GELU) {
                        v0 = 0.5f * v0 * (1.f + erff(v0 * 0.70710678118654752f));
                        v1 = 0.5f * v1 * (1.f + erff(v1 * 0.70710678118654752f));
                        v2 = 0.5f * v2 * (1.f + erff(v2 * 0.70710678118654752f));
                        v3 = 0.5f * v3 * (1.f + erff(v3 * 0.70710678118654752f));
                    }
                    if constexpr (std::is_same<TOUT, float>::value) {
                        *(float4*)&outp[rb + colb] = make_float4(v0, v1, v2, v3);
                    } else {
                        uint2 p; p.x = pack2(v0, v1); p.y = pack2(v2, v3);
                        *(uint2*)&outp[rb + colb] = p;
                    }
                }
            }
        }
    }
}

// ---------- legacy small-workspace kernels (proven, fp32 inputs) --------------------
template<int GELU, typename TA, typename TW, typename TOUT>
__global__ __launch_bounds__(256, 4) void expert_layer(
    const TA* __restrict__ in, const TW* __restrict__ W,
    const float* __restrict__ bias, const int* __restrict__ cnt,
    const int* __restrict__ list, TOUT* __restrict__ outp)
{
    constexpr int BK = 64, LDK = 72;
    constexpr bool A_F32 = std::is_same<TA, float>::value;
    constexpr bool W_F32 = std::is_same<TW, float>::value;
    __shared__ __align__(16) unsigned short At[2][64][LDK];
    __shared__ __align__(16) unsigned short Bt[2][64][LDK];
    __shared__ int toks[64];

    const int bx = blockIdx.x;
    const int e = bx / 12, nb = bx % 12;
    const int c = cnt[e];
    const int n0 = nb * 64;
    const int tid = threadIdx.x, lane = tid & 63, w = tid >> 6;
    const int rg = w & 1, cgp = w >> 1;
    const int l15 = lane & 15, q8 = (lane >> 4) * 8, q = lane >> 4;
    const int sr = tid >> 2, sk = (tid & 3) * 16;

    const TW* bsrc = W + (size_t)e * DMODEL * DMODEL + (size_t)(n0 + sr) * DMODEL + sk;
    const int* lst = list + e * T_TOK;

    uint4 pa[2], pb[2];
    float4 fa[4], fb[4];

    for (int yt = blockIdx.y; yt * 64 < c; yt += 8) {
        const int m0 = yt * 64;
        __syncthreads();
        if (tid < 64) {
            int mi = m0 + tid;
            toks[tid] = lst[mi < c ? mi : c - 1];
        }
        int ma = m0 + sr;
        const TA* asrc = in + (size_t)lst[ma < c ? ma : c - 1] * DMODEL + sk;

        f32x4 acc[2][2];
#pragma unroll
        for (int i = 0; i < 2; ++i)
#pragma unroll
            for (int j = 0; j < 2; ++j) acc[i][j] = (f32x4){0.f, 0.f, 0.f, 0.f};

        auto load_regs = [&](int k0) {
            if constexpr (A_F32) {
                const float4* s = (const float4*)(asrc + k0);
                fa[0] = s[0]; fa[1] = s[1]; fa[2] = s[2]; fa[3] = s[3];
            } else {
                const uint4* s = (const uint4*)(asrc + k0);
                pa[0] = s[0]; pa[1] = s[1];
            }
            if constexpr (W_F32) {
                const float4* s = (const float4*)(bsrc + k0);
                fb[0] = s[0]; fb[1] = s[1]; fb[2] = s[2]; fb[3] = s[3];
            } else {
                const uint4* s = (const uint4*)(bsrc + k0);
                pb[0] = s[0]; pb[1] = s[1];
            }
        };
        auto store_tiles = [&](int buf) {
            if constexpr (A_F32) {
                uint4 w0, w1;
                w0.x = pack2(fa[0].x, fa[0].y); w0.y = pack2(fa[0].z, fa[0].w);
                w0.z = pack2(fa[1].x, fa[1].y); w0.w = pack2(fa[1].z, fa[1].w);
                w1.x = pack2(fa[2].x, fa[2].y); w1.y = pack2(fa[2].z, fa[2].w);
                w1.z = pack2(fa[3].x, fa[3].y); w1.w = pack2(fa[3].z, fa[3].w);
                *(uint4*)&At[buf][sr][sk] = w0; *(uint4*)&At[buf][sr][sk + 8] = w1;
            } else {
                *(uint4*)&At[buf][sr][sk] = pa[0]; *(uint4*)&At[buf][sr][sk + 8] = pa[1];
            }
            if constexpr (W_F32) {
                uint4 w0, w1;
                w0.x = pack2(fb[0].x, fb[0].y); w0.y = pack2(fb[0].z, fb[0].w);
                w0.z = pack2(fb[1].x, fb[1].y); w0.w = pack2(fb[1].z, fb[1].w);
                w1.x = pack2(fb[2].x, fb[2].y); w1.y = pack2(fb[2].z, fb[2].w);
                w1.z = pack2(fb[3].x, fb[3].y); w1.w = pack2(fb[3].z, fb[3].w);
                *(uint4*)&Bt[buf][sr][sk] = w0; *(uint4*)&Bt[buf][sr][sk + 8] = w1;
            } else {
                *(uint4*)&Bt[buf][sr][sk] = pb[0]; *(uint4*)&Bt[buf][sr][sk + 8] = pb[1];
            }
        };

        load_regs(0);
        store_tiles(0);
#pragma unroll 1
        for (int it = 0; it < DMODEL / BK; ++it) {
            __syncthreads();
            if (it + 1 < DMODEL / BK) load_regs((it + 1) * BK);
            const int buf = it & 1;
#pragma unroll
            for (int kk = 0; kk < BK; kk += 32) {
                bf16x8 a0 = *(const bf16x8*)&At[buf][rg * 32 + l15][kk + q8];
                bf16x8 a1 = *(const bf16x8*)&At[buf][rg * 32 + 16 + l15][kk + q8];
                bf16x8 b0 = *(const bf16x8*)&Bt[buf][cgp * 32 + l15][kk + q8];
                bf16x8 b1 = *(const bf16x8*)&Bt[buf][cgp * 32 + 16 + l15][kk + q8];
                acc[0][0] = __builtin_amdgcn_mfma_f32_16x16x32_bf16(a0, b0, acc[0][0], 0, 0, 0);
                acc[0][1] = __builtin_amdgcn_mfma_f32_16x16x32_bf16(a0, b1, acc[0][1], 0, 0, 0);
                acc[1][0] = __builtin_amdgcn_mfma_f32_16x16x32_bf16(a1, b0, acc[1][0], 0, 0, 0);
                acc[1][1] = __builtin_amdgcn_mfma_f32_16x16x32_bf16(a1, b1, acc[1][1], 0, 0, 0);
            }
            if (it + 1 < DMODEL / BK) store_tiles(buf ^ 1);
        }

#pragma unroll
        for (int i = 0; i < 2; ++i) {
#pragma unroll
            for (int j = 0; j < 2; ++j) {
                int col = n0 + cgp * 32 + j * 16 + l15;
                float bv = bias[e * DMODEL + col];
#pragma unroll
                for (int r = 0; r < 4; ++r) {
                    int mrow = rg * 32 + i * 16 + q * 4 + r;
                    if (m0 + mrow < c) {
                        float val = acc[i][j][r] + bv;
                        if (GELU) val = 0.5f * val * (1.f + erff(val * 0.70710678118654752f));
                        size_t idx = (size_t)toks[mrow] * DMODEL + col;
                        if constexpr (std::is_same<TOUT, float>::value) outp[idx] = val;
                        else outp[idx] = f2bf(val);
                    }
                }
            }
        }
    }
}

// ---------- launch ------------------------------------------------------------------
extern "C" void kernel_launch(void* const* d_in, const int* in_sizes, int n_in,
                              void* d_out, int out_size, void* d_ws, size_t ws_size,
                              hipStream_t stream)
{
    const float* x  = (const float*)d_in[0];
    const float* W1 = (const float*)d_in[1];
    const float* b1 = (const float*)d_in[2];
    const float* W2 = (const float*)d_in[3];
    const float* b2 = (const float*)d_in[4];
    const float* Wg = (const float*)d_in[5];
    const float* bg = (const float*)d_in[6];
    float* out = (float*)d_out;

    char* ws   = (char*)d_ws;
    int*  cnt  = (int*)ws;                                  // 64 B
    int*  list = (int*)(ws + 256);                          // 403,456 B
    unsigned short* xb  = (unsigned short*)(ws + 403712);   // 9,682,944 B
    unsigned short* h   = (unsigned short*)(ws + 10086656); // 9,682,944 B
    unsigned short* w1b = (unsigned short*)(ws + 19769600); // 18,874,368 B
    unsigned short* w2b = (unsigned short*)(ws + 38643968); // 18,874,368 B
    const bool big = ws_size >= (size_t)57518336;

    hipMemsetAsync(cnt, 0, 256, stream);
    dim3 grid(12 * NEXP, 8);   // 192 x 8; persistent y-stride, no dead blocks
    if (big) {
        prep_kernel<<<dim3(NGATE + 9216), dim3(256), 0, stream>>>(
            x, Wg, bg, W1, W2, cnt, list, xb, w1b, w2b);
        // L1: gathered bf16 x -> packed bf16 h (dense stores, 8B/lane contiguous)
        expert_gemm<1, 0, 1, unsigned short>
            <<<grid, dim3(256), 0, stream>>>(xb, w1b, b1, cnt, list, h);
        // L2: packed bf16 h -> scattered fp32 out (16B/lane, 128B/row/wave contiguous)
        expert_gemm<0, 1, 0, float>
            <<<grid, dim3(256), 0, stream>>>(h, w2b, b2, cnt, list, out);
    } else {   // fallback: fp32 inputs with fused bf16 staging (proven path)
        prep_kernel<<<dim3(NGATE), dim3(256), 0, stream>>>(
            x, Wg, bg, W1, W2, cnt, list, nullptr, nullptr, nullptr);
        expert_layer<1, float, float, unsigned short>
            <<<grid, dim3(256), 0, stream>>>(x, W1, b1, cnt, list, h);
        expert_layer<0, unsigned short, float, float>
            <<<grid, dim3(256), 0, stream>>>(h, W2, b2, cnt, list, out);
    }
}

// Round 4
// 323.545 us; speedup vs baseline: 2.3660x; 1.0735x over previous
//
#include <hip/hip_runtime.h>
#include <hip/hip_bf16.h>
#include <math.h>
#include <type_traits>

// MoE: E=16, D=H=768, T=6304 tokens; fp32 in/out, bf16 internally for MFMA.
// R4: no weight pre-conversion. Gate-only prep; GEMMs read fp32 weights directly
//     and convert to bf16 during LDS staging (proven legacy path).
#define T_TOK 6304
#define DMODEL 768
#define NEXP 16
#define NGATE 394            // 6304 / 16 tokens per gate unit

typedef __bf16 bf16x8 __attribute__((ext_vector_type(8)));
typedef float f32x4 __attribute__((ext_vector_type(4)));

__device__ __forceinline__ unsigned short f2bf(float f) {
    __hip_bfloat16 b = __float2bfloat16(f);   // RNE
    return __builtin_bit_cast(unsigned short, b);
}
__device__ __forceinline__ unsigned int pack2(float lo, float hi) {
    return (unsigned int)f2bf(lo) | ((unsigned int)f2bf(hi) << 16);
}

// ---------- prep: gate only (+x->bf16 emission). 394 blocks. ------------------------
__global__ __launch_bounds__(256) void gate_kernel(
    const float* __restrict__ x, const float* __restrict__ Wg,
    const float* __restrict__ bg, int* __restrict__ cnt, int* __restrict__ list,
    unsigned short* __restrict__ xb)
{
    // thread=(token,expert), fp64 dot, strict first-max argmax (np semantics)
    __shared__ double lg[16][17];
    const int tt = threadIdx.x >> 4;
    const int e  = threadIdx.x & 15;
    const int t  = blockIdx.x * 16 + tt;     // 6304 = 394*16
    const float4* xr = (const float4*)(x + (size_t)t * DMODEL);
    const float4* wr = (const float4*)(Wg + (size_t)e * DMODEL);
    double s0 = 0, s1 = 0, s2 = 0, s3 = 0;
#pragma unroll 4
    for (int i = 0; i < DMODEL / 4; ++i) {
        float4 a = xr[i], w = wr[i];
        s0 += (double)a.x * (double)w.x;
        s1 += (double)a.y * (double)w.y;
        s2 += (double)a.z * (double)w.z;
        s3 += (double)a.w * (double)w.w;
    }
    lg[tt][e] = (s0 + s1) + (s2 + s3);
    if (xb) {   // emit x row slice [e*48, e*48+48) as bf16
        uint4* dst = (uint4*)(xb + (size_t)t * DMODEL + e * 48);
#pragma unroll
        for (int u = 0; u < 6; ++u) {
            float4 a = xr[e * 12 + 2 * u], b = xr[e * 12 + 2 * u + 1];
            dst[u] = make_uint4(pack2(a.x, a.y), pack2(a.z, a.w),
                                pack2(b.x, b.y), pack2(b.z, b.w));
        }
    }
    __syncthreads();
    if (e == 0) {
        double best = -1e300; int bi = 0;
#pragma unroll
        for (int k = 0; k < NEXP; ++k) {
            double v = lg[tt][k] + (double)bg[k];
            if (v > best) { best = v; bi = k; }
        }
        int pos = atomicAdd(&cnt[bi], 1);
        list[bi * T_TOK + pos] = t;
    }
}

// ---------- gathered expert GEMM: proven (192,8) persistent-y structure -------------
// BM=BN=BK=64, 4 waves, wave tile 32x32, double-buffered LDS, 1 barrier per K-iter.
// A = bf16 (xb or packed h). W: TW=float -> convert to bf16 in store_tiles (in-reg).
// SWAPPED MFMA operands: acc[i][j] = mfma(w_frag_j, tok_frag_i, acc) =>
//   D col = lane&15 = token-in-16, D row = (lane>>4)*4+reg = weight col (4 contig).
// Lane stores 4 consecutive out cols of one token row: 8B (bf16) / 16B (fp32).
// PACKED_IN : A rows dense at off[e]+row (list order). PACKED_OUT: same for output.
template<int GELU, int PACKED_IN, int PACKED_OUT, typename TW, typename TOUT>
__global__ __launch_bounds__(256, 4) void expert_gemm(
    const unsigned short* __restrict__ in, const TW* __restrict__ Wb,
    const float* __restrict__ bias, const int* __restrict__ cnt,
    const int* __restrict__ list, TOUT* __restrict__ outp)
{
    constexpr int BK = 64, LDK = 72;   // pad 72: 144B row stride, 2-way alias (free)
    constexpr bool W_F32 = std::is_same<TW, float>::value;
    __shared__ __align__(16) unsigned short At[2][64][LDK];
    __shared__ __align__(16) unsigned short Bt[2][64][LDK];
    __shared__ int toks[64];

    const int bx = blockIdx.x;              // = e*12 + nb : consecutive bx spread XCDs
    const int e = bx / 12, nb = bx % 12;
    const int c = cnt[e];
    int off = 0;
    if (PACKED_IN || PACKED_OUT)
        for (int k = 0; k < e; ++k) off += cnt[k];   // prefix base of expert e
    const int n0 = nb * 64;
    const int tid = threadIdx.x, lane = tid & 63, w = tid >> 6;
    const int rg = w & 1, cgp = w >> 1;
    const int l15 = lane & 15, q8 = (lane >> 4) * 8, q = lane >> 4;
    const int sr = tid >> 2, sk = (tid & 3) * 16;

    const TW* bsrc = Wb + (size_t)e * DMODEL * DMODEL + (size_t)(n0 + sr) * DMODEL + sk;
    const int* lst = list + e * T_TOK;

    uint4 pa[2], pb[2];
    float4 fb[4];

    for (int yt = blockIdx.y; yt * 64 < c; yt += 8) {
        const int m0 = yt * 64;
        __syncthreads();                     // prior y-iter epilogue done (LDS reuse)
        if (!PACKED_OUT && tid < 64) {
            int mi = m0 + tid;
            toks[tid] = lst[mi < c ? mi : c - 1];
        }
        const int ma0 = m0 + sr;
        const int mac = ma0 < c ? ma0 : c - 1;
        const unsigned short* asrc = PACKED_IN
            ? in + (size_t)(off + mac) * DMODEL + sk
            : in + (size_t)lst[mac] * DMODEL + sk;

        f32x4 acc[2][2];
#pragma unroll
        for (int i = 0; i < 2; ++i)
#pragma unroll
            for (int j = 0; j < 2; ++j) acc[i][j] = (f32x4){0.f, 0.f, 0.f, 0.f};

        auto load_regs = [&](int k0) {
            const uint4* s = (const uint4*)(asrc + k0);
            pa[0] = s[0]; pa[1] = s[1];
            if constexpr (W_F32) {
                const float4* t2 = (const float4*)(bsrc + k0);
                fb[0] = t2[0]; fb[1] = t2[1]; fb[2] = t2[2]; fb[3] = t2[3];
            } else {
                const uint4* t2 = (const uint4*)(bsrc + k0);
                pb[0] = t2[0]; pb[1] = t2[1];
            }
        };
        auto store_tiles = [&](int buf) {
            *(uint4*)&At[buf][sr][sk] = pa[0]; *(uint4*)&At[buf][sr][sk + 8] = pa[1];
            if constexpr (W_F32) {
                uint4 w0, w1;
                w0.x = pack2(fb[0].x, fb[0].y); w0.y = pack2(fb[0].z, fb[0].w);
                w0.z = pack2(fb[1].x, fb[1].y); w0.w = pack2(fb[1].z, fb[1].w);
                w1.x = pack2(fb[2].x, fb[2].y); w1.y = pack2(fb[2].z, fb[2].w);
                w1.z = pack2(fb[3].x, fb[3].y); w1.w = pack2(fb[3].z, fb[3].w);
                *(uint4*)&Bt[buf][sr][sk] = w0; *(uint4*)&Bt[buf][sr][sk + 8] = w1;
            } else {
                *(uint4*)&Bt[buf][sr][sk] = pb[0]; *(uint4*)&Bt[buf][sr][sk + 8] = pb[1];
            }
        };

        load_regs(0);
        store_tiles(0);
#pragma unroll 1
        for (int it = 0; it < DMODEL / BK; ++it) {
            __syncthreads();                 // buf[it&1] ready
            if (it + 1 < DMODEL / BK) load_regs((it + 1) * BK);
            const int buf = it & 1;
#pragma unroll
            for (int kk = 0; kk < BK; kk += 32) {
                bf16x8 a0 = *(const bf16x8*)&At[buf][rg * 32 + l15][kk + q8];
                bf16x8 a1 = *(const bf16x8*)&At[buf][rg * 32 + 16 + l15][kk + q8];
                bf16x8 b0 = *(const bf16x8*)&Bt[buf][cgp * 32 + l15][kk + q8];
                bf16x8 b1 = *(const bf16x8*)&Bt[buf][cgp * 32 + 16 + l15][kk + q8];
                acc[0][0] = __builtin_amdgcn_mfma_f32_16x16x32_bf16(b0, a0, acc[0][0], 0, 0, 0);
                acc[0][1] = __builtin_amdgcn_mfma_f32_16x16x32_bf16(b1, a0, acc[0][1], 0, 0, 0);
                acc[1][0] = __builtin_amdgcn_mfma_f32_16x16x32_bf16(b0, a1, acc[1][0], 0, 0, 0);
                acc[1][1] = __builtin_amdgcn_mfma_f32_16x16x32_bf16(b1, a1, acc[1][1], 0, 0, 0);
            }
            if (it + 1 < DMODEL / BK) store_tiles(buf ^ 1);  // peers read buf only
        }

        // epilogue: lane's token row = rg*32+i*16+l15; cols colb..colb+3 contiguous
#pragma unroll
        for (int i = 0; i < 2; ++i) {
            const int mrow = rg * 32 + i * 16 + l15;
            if (m0 + mrow < c) {
                const size_t rb = PACKED_OUT
                    ? (size_t)(off + m0 + mrow) * DMODEL
                    : (size_t)toks[mrow] * DMODEL;
#pragma unroll
                for (int j = 0; j < 2; ++j) {
                    const int colb = n0 + cgp * 32 + j * 16 + q * 4;
                    const float4 bv = *(const float4*)&bias[e * DMODEL + colb];
                    float v0 = acc[i][j][0] + bv.x;
                    float v1 = acc[i][j][1] + bv.y;
                    float v2 = acc[i][j][2] + bv.z;
                    float v3 = acc[i][j][3] + bv.w;
                    if (GELU) {
                        v0 = 0.5f * v0 * (1.f + erff(v0 * 0.70710678118654752f));
                        v1 = 0.5f * v1 * (1.f + erff(v1 * 0.70710678118654752f));
                        v2 = 0.5f * v2 * (1.f + erff(v2 * 0.70710678118654752f));
                        v3 = 0.5f * v3 * (1.f + erff(v3 * 0.70710678118654752f));
                    }
                    if constexpr (std::is_same<TOUT, float>::value) {
                        *(float4*)&outp[rb + colb] = make_float4(v0, v1, v2, v3);
                    } else {
                        uint2 p; p.x = pack2(v0, v1); p.y = pack2(v2, v3);
                        *(uint2*)&outp[rb + colb] = p;
                    }
                }
            }
        }
    }
}

// ---------- legacy small-workspace kernel (proven, fp32 A input) --------------------
template<int GELU, typename TA, typename TW, typename TOUT>
__global__ __launch_bounds__(256, 4) void expert_layer(
    const TA* __restrict__ in, const TW* __restrict__ W,
    const float* __restrict__ bias, const int* __restrict__ cnt,
    const int* __restrict__ list, TOUT* __restrict__ outp)
{
    constexpr int BK = 64, LDK = 72;
    constexpr bool A_F32 = std::is_same<TA, float>::value;
    constexpr bool W_F32 = std::is_same<TW, float>::value;
    __shared__ __align__(16) unsigned short At[2][64][LDK];
    __shared__ __align__(16) unsigned short Bt[2][64][LDK];
    __shared__ int toks[64];

    const int bx = blockIdx.x;
    const int e = bx / 12, nb = bx % 12;
    const int c = cnt[e];
    const int n0 = nb * 64;
    const int tid = threadIdx.x, lane = tid & 63, w = tid >> 6;
    const int rg = w & 1, cgp = w >> 1;
    const int l15 = lane & 15, q8 = (lane >> 4) * 8, q = lane >> 4;
    const int sr = tid >> 2, sk = (tid & 3) * 16;

    const TW* bsrc = W + (size_t)e * DMODEL * DMODEL + (size_t)(n0 + sr) * DMODEL + sk;
    const int* lst = list + e * T_TOK;

    uint4 pa[2], pb[2];
    float4 fa[4], fb[4];

    for (int yt = blockIdx.y; yt * 64 < c; yt += 8) {
        const int m0 = yt * 64;
        __syncthreads();
        if (tid < 64) {
            int mi = m0 + tid;
            toks[tid] = lst[mi < c ? mi : c - 1];
        }
        int ma = m0 + sr;
        const TA* asrc = in + (size_t)lst[ma < c ? ma : c - 1] * DMODEL + sk;

        f32x4 acc[2][2];
#pragma unroll
        for (int i = 0; i < 2; ++i)
#pragma unroll
            for (int j = 0; j < 2; ++j) acc[i][j] = (f32x4){0.f, 0.f, 0.f, 0.f};

        auto load_regs = [&](int k0) {
            if constexpr (A_F32) {
                const float4* s = (const float4*)(asrc + k0);
                fa[0] = s[0]; fa[1] = s[1]; fa[2] = s[2]; fa[3] = s[3];
            } else {
                const uint4* s = (const uint4*)(asrc + k0);
                pa[0] = s[0]; pa[1] = s[1];
            }
            if constexpr (W_F32) {
                const float4* s = (const float4*)(bsrc + k0);
                fb[0] = s[0]; fb[1] = s[1]; fb[2] = s[2]; fb[3] = s[3];
            } else {
                const uint4* s = (const uint4*)(bsrc + k0);
                pb[0] = s[0]; pb[1] = s[1];
            }
        };
        auto store_tiles = [&](int buf) {
            if constexpr (A_F32) {
                uint4 w0, w1;
                w0.x = pack2(fa[0].x, fa[0].y); w0.y = pack2(fa[0].z, fa[0].w);
                w0.z = pack2(fa[1].x, fa[1].y); w0.w = pack2(fa[1].z, fa[1].w);
                w1.x = pack2(fa[2].x, fa[2].y); w1.y = pack2(fa[2].z, fa[2].w);
                w1.z = pack2(fa[3].x, fa[3].y); w1.w = pack2(fa[3].z, fa[3].w);
                *(uint4*)&At[buf][sr][sk] = w0; *(uint4*)&At[buf][sr][sk + 8] = w1;
            } else {
                *(uint4*)&At[buf][sr][sk] = pa[0]; *(uint4*)&At[buf][sr][sk + 8] = pa[1];
            }
            if constexpr (W_F32) {
                uint4 w0, w1;
                w0.x = pack2(fb[0].x, fb[0].y); w0.y = pack2(fb[0].z, fb[0].w);
                w0.z = pack2(fb[1].x, fb[1].y); w0.w = pack2(fb[1].z, fb[1].w);
                w1.x = pack2(fb[2].x, fb[2].y); w1.y = pack2(fb[2].z, fb[2].w);
                w1.z = pack2(fb[3].x, fb[3].y); w1.w = pack2(fb[3].z, fb[3].w);
                *(uint4*)&Bt[buf][sr][sk] = w0; *(uint4*)&Bt[buf][sr][sk + 8] = w1;
            } else {
                *(uint4*)&Bt[buf][sr][sk] = pb[0]; *(uint4*)&Bt[buf][sr][sk + 8] = pb[1];
            }
        };

        load_regs(0);
        store_tiles(0);
#pragma unroll 1
        for (int it = 0; it < DMODEL / BK; ++it) {
            __syncthreads();
            if (it + 1 < DMODEL / BK) load_regs((it + 1) * BK);
            const int buf = it & 1;
#pragma unroll
            for (int kk = 0; kk < BK; kk += 32) {
                bf16x8 a0 = *(const bf16x8*)&At[buf][rg * 32 + l15][kk + q8];
                bf16x8 a1 = *(const bf16x8*)&At[buf][rg * 32 + 16 + l15][kk + q8];
                bf16x8 b0 = *(const bf16x8*)&Bt[buf][cgp * 32 + l15][kk + q8];
                bf16x8 b1 = *(const bf16x8*)&Bt[buf][cgp * 32 + 16 + l15][kk + q8];
                acc[0][0] = __builtin_amdgcn_mfma_f32_16x16x32_bf16(a0, b0, acc[0][0], 0, 0, 0);
                acc[0][1] = __builtin_amdgcn_mfma_f32_16x16x32_bf16(a0, b1, acc[0][1], 0, 0, 0);
                acc[1][0] = __builtin_amdgcn_mfma_f32_16x16x32_bf16(a1, b0, acc[1][0], 0, 0, 0);
                acc[1][1] = __builtin_amdgcn_mfma_f32_16x16x32_bf16(a1, b1, acc[1][1], 0, 0, 0);
            }
            if (it + 1 < DMODEL / BK) store_tiles(buf ^ 1);
        }

#pragma unroll
        for (int i = 0; i < 2; ++i) {
#pragma unroll
            for (int j = 0; j < 2; ++j) {
                int col = n0 + cgp * 32 + j * 16 + l15;
                float bv = bias[e * DMODEL + col];
#pragma unroll
                for (int r = 0; r < 4; ++r) {
                    int mrow = rg * 32 + i * 16 + q * 4 + r;
                    if (m0 + mrow < c) {
                        float val = acc[i][j][r] + bv;
                        if (GELU) val = 0.5f * val * (1.f + erff(val * 0.70710678118654752f));
                        size_t idx = (size_t)toks[mrow] * DMODEL + col;
                        if constexpr (std::is_same<TOUT, float>::value) outp[idx] = val;
                        else outp[idx] = f2bf(val);
                    }
                }
            }
        }
    }
}

// ---------- launch ------------------------------------------------------------------
extern "C" void kernel_launch(void* const* d_in, const int* in_sizes, int n_in,
                              void* d_out, int out_size, void* d_ws, size_t ws_size,
                              hipStream_t stream)
{
    const float* x  = (const float*)d_in[0];
    const float* W1 = (const float*)d_in[1];
    const float* b1 = (const float*)d_in[2];
    const float* W2 = (const float*)d_in[3];
    const float* b2 = (const float*)d_in[4];
    const float* Wg = (const float*)d_in[5];
    const float* bg = (const float*)d_in[6];
    float* out = (float*)d_out;

    char* ws   = (char*)d_ws;
    int*  cnt  = (int*)ws;                                  // 64 B
    int*  list = (int*)(ws + 256);                          // 403,456 B
    unsigned short* xb  = (unsigned short*)(ws + 403712);   // 9,682,944 B
    unsigned short* h   = (unsigned short*)(ws + 10086656); // 9,682,944 B
    const bool big = ws_size >= (size_t)19769600;

    hipMemsetAsync(cnt, 0, 256, stream);
    dim3 grid(12 * NEXP, 8);   // 192 x 8; persistent y-stride, no dead blocks
    if (big) {
        // gate only: ~30 MB traffic vs old prep's ~280 MB (weight convert removed)
        gate_kernel<<<dim3(NGATE), dim3(256), 0, stream>>>(
            x, Wg, bg, cnt, list, xb);
        // L1: gathered bf16 x @ fp32 W1 (in-reg convert) -> packed bf16 h
        expert_gemm<1, 0, 1, float, unsigned short>
            <<<grid, dim3(256), 0, stream>>>(xb, W1, b1, cnt, list, h);
        // L2: packed bf16 h @ fp32 W2 (in-reg convert) -> scattered fp32 out
        expert_gemm<0, 1, 0, float, float>
            <<<grid, dim3(256), 0, stream>>>(h, W2, b2, cnt, list, out);
    } else {   // fallback: fp32 A input with fused bf16 staging (proven path)
        gate_kernel<<<dim3(NGATE), dim3(256), 0, stream>>>(
            x, Wg, bg, cnt, list, nullptr);
        expert_layer<1, float, float, unsigned short>
            <<<grid, dim3(256), 0, stream>>>(x, W1, b1, cnt, list, h);
        expert_layer<0, unsigned short, float, float>
            <<<grid, dim3(256), 0, stream>>>(h, W2, b2, cnt, list, out);
    }
}